// Round 1
// 1532.622 us; speedup vs baseline: 1.1709x; 1.1709x over previous
//
#include <hip/hip_runtime.h>
#include <stdint.h>

// GRU forward: V=32000 E=128 H=256 B=8 S=512.
// Reference dtypes are float32; a detector kernel resolves f32-vs-bf16 storage
// at runtime and exactly one templated variant of each kernel does the work.
// ws: gi f32 [512][8][768] (12.58MB) | hidden fp16 [4096][256] (2.1MB) | flag
//
// k_scan v2: one CU per batch (8 blocks x 1024 thr). Batches are independent
// recurrences, so the M=16 MFMA padding is paid once per CU either way; 8 CUs
// cut all non-MFMA per-step cost 8x. w_hh rows are grouped as gate-triples so
// each wave's 3 MFMA tiles (r,z,n) for its 16 j's land in the same lanes ->
// gate math in-register, no gh LDS round-trip, 1 barrier/step.

typedef __attribute__((ext_vector_type(8))) _Float16 half8;   // 4 VGPRs
typedef __attribute__((ext_vector_type(4))) _Float16 half4;   // 2 VGPRs
typedef __attribute__((ext_vector_type(4))) float float4v;
typedef __attribute__((ext_vector_type(4))) float facc4;      // MFMA acc
typedef __attribute__((ext_vector_type(4))) unsigned short ushort4v;

#define GI_BYTES   (512 * 8 * 768 * 4)        // 12582912
#define HID_BYTES  (4096 * 256 * 2)           // 2097152
#define FLAG_OFF   (GI_BYTES + HID_BYTES)

__device__ __forceinline__ float b2f(unsigned short u) {
  union { unsigned int i; float f; } v; v.i = ((unsigned int)u) << 16; return v.f;
}
__device__ __forceinline__ unsigned short f2b(float f) {
  union { float f; unsigned int i; } v; v.f = f;
  unsigned int r = v.i + 0x7FFFu + ((v.i >> 16) & 1u);  // RNE
  return (unsigned short)(r >> 16);
}
template<bool BF> __device__ __forceinline__ float ldf(const void* p, int i) {
  if constexpr (BF) return b2f(((const unsigned short*)p)[i]);
  else              return ((const float*)p)[i];
}
template<bool BF> __device__ __forceinline__ float4v ld4(const void* p, int i) {
  float4v r;
  if constexpr (BF) {
    ushort4v u = *reinterpret_cast<const ushort4v*>((const unsigned short*)p + i);
#pragma unroll
    for (int j = 0; j < 4; ++j) r[j] = b2f(u[j]);
  } else {
    r = *reinterpret_cast<const float4v*>((const float*)p + i);
  }
  return r;
}

// ---- dtype detector: bf16 storage => low u16 of each u32 word has a small-
// value bf16 exponent pattern; f32 storage => those bits are uniform mantissa.
__global__ void k_detect(const unsigned int* __restrict__ emb_raw,
                         int* __restrict__ flag) {
  int tid = threadIdx.x;
  unsigned int u = emb_raw[tid];
  unsigned int lo = u & 0xFFFFu;
  unsigned int ex = (lo >> 7) & 0xFFu;        // bf16 exponent field
  int hit = ((ex >= 96u && ex <= 127u) || lo == 0u) ? 1 : 0;
  unsigned long long m = __ballot(hit);
  if (tid == 0) flag[0] = (__popcll(m) >= 40) ? 1 : 0;
}

// ---- kernel 1: gi[s][b][g] = emb[t[b,s]] . w_ih[g,:] + b_ih[g]  (f32 out) ----
template<bool BF>
__global__ __launch_bounds__(256, 4) void k_gi(
    const int* __restrict__ flag, const int* __restrict__ t,
    const void* __restrict__ emb, const void* __restrict__ w_ih,
    const void* __restrict__ b_ih, float* __restrict__ gi)
{
  if (*flag != (BF ? 1 : 0)) return;
  alignas(16) __shared__ float x_lds[4][128];
  const int n0 = blockIdx.x * 4;               // 4 tokens per block
  const int tid = threadIdx.x;
  for (int i = tid; i < 512; i += 256) {
    int tk = i >> 7, e = i & 127;
    int n = n0 + tk, s = n >> 3, b = n & 7;
    int tok = t[b * 512 + s];
    x_lds[tk][e] = ldf<BF>(emb, tok * 128 + e);
  }
  __syncthreads();
#pragma unroll
  for (int gg = 0; gg < 3; ++gg) {
    int g = gg * 256 + tid;
    float bias = ldf<BF>(b_ih, g);
    float a0 = bias, a1 = bias, a2 = bias, a3 = bias;
    for (int kb = 0; kb < 32; ++kb) {
      float4v w4 = ld4<BF>(w_ih, g * 128 + kb * 4);
#pragma unroll
      for (int j = 0; j < 4; ++j) {
        float w = w4[j]; int k = kb * 4 + j;
        a0 = fmaf(w, x_lds[0][k], a0);
        a1 = fmaf(w, x_lds[1][k], a1);
        a2 = fmaf(w, x_lds[2][k], a2);
        a3 = fmaf(w, x_lds[3][k], a3);
      }
    }
    gi[(n0 + 0) * 768 + g] = a0;
    gi[(n0 + 1) * 768 + g] = a1;
    gi[(n0 + 2) * 768 + g] = a2;
    gi[(n0 + 3) * 768 + g] = a3;
  }
}

// ---- kernel 2: serial GRU scan, one block per batch, 16 waves ----
// Per step gh[1,768] = h[1,256] @ w_hh^T via fp16 mfma 16x16x32 (M=16 pad,
// 1 valid row). Wave w holds gate-triple tiles {r,z,n} for j in [16w,16w+16):
// bfr[3][8] = 24 half8 = 96 VGPRs. A-frag reads exec-masked to l15==0 lanes.
template<bool BF>
__global__ __launch_bounds__(1024, 4) void k_scan(
    const int* __restrict__ flag, const void* __restrict__ w_hh,
    const void* __restrict__ b_hh, const void* __restrict__ h0,
    const float* __restrict__ gi, _Float16* __restrict__ hidden)
{
  if (*flag != (BF ? 1 : 0)) return;
  alignas(16) __shared__ _Float16 a_sh[2][256];   // h double-buffer, 1KB
  alignas(16) __shared__ float gi_sh[2][768];     // gi double-buffer, 6KB
  alignas(16) __shared__ float bhh_sh[768];       // 3KB

  const int tid = threadIdx.x;
  const int b = blockIdx.x;                       // batch index
  const int wave = tid >> 6, lane = tid & 63;
  const int l15 = lane & 15, q = lane >> 4;
  const bool ard = (l15 == 0);                    // only row 0 of A is real
  const int qo = q * 8;                           // k sub-offset within kt

  // B fragments: tile tt = gate (r,z,n), cols j in [wave*16, wave*16+16).
  // B[k][col] = w_hh[row][k]; lane: col=l15 -> row = tt*256 + wave*16 + l15,
  // k = kt*32 + q*8 + j. Same frag mapping as the verified previous kernel.
  half8 bfr[3][8];
#pragma unroll
  for (int tt = 0; tt < 3; ++tt) {
    int nrow = tt * 256 + (wave << 4) + l15;
#pragma unroll
    for (int kt = 0; kt < 8; ++kt) {
      int base = nrow * 256 + kt * 32 + qo;
      float4v x0 = ld4<BF>(w_hh, base), x1 = ld4<BF>(w_hh, base + 4);
      half8 h;
#pragma unroll
      for (int jj = 0; jj < 4; ++jj) { h[jj] = (_Float16)x0[jj]; h[4 + jj] = (_Float16)x1[jj]; }
      bfr[tt][kt] = h;
    }
  }

  if (tid < 768) bhh_sh[tid] = ldf<BF>(b_hh, tid);
  if (tid < 256) a_sh[0][tid] = (_Float16)ldf<BF>(h0, tid);   // h0 broadcast
  if (tid < 768) gi_sh[0][tid] = gi[b * 768 + tid];           // gi(s=0)
  float hreg = 0.f;
  if (lane < 16) hreg = ldf<BF>(h0, (wave << 4) + lane);      // f32 across steps

  half8 a0 = {}, a1 = {};   // inactive lanes (l15!=0) stay zero forever
  _Float16* hid = hidden + b * 512 * 256;
  __syncthreads();

  int p = 0;
  for (int s = 0; s < 512; ++s) {
    // prefetch gi(s+1) into a reg; HBM/L3 latency hides under the MFMA phase
    float gnext = 0.f;
    if (tid < 768 && s < 511) gnext = gi[(s + 1) * 6144 + b * 768 + tid];

    const _Float16* ap = &a_sh[p][0];
    facc4 acc0 = {}, acc1 = {}, acc2 = {};
    if (ard) a0 = *reinterpret_cast<const half8*>(ap + qo);
#pragma unroll
    for (int kt = 0; kt < 8; kt += 2) {
      if (ard) a1 = *reinterpret_cast<const half8*>(ap + (kt + 1) * 32 + qo);
      acc0 = __builtin_amdgcn_mfma_f32_16x16x32_f16(a0, bfr[0][kt], acc0, 0, 0, 0);
      acc1 = __builtin_amdgcn_mfma_f32_16x16x32_f16(a0, bfr[1][kt], acc1, 0, 0, 0);
      acc2 = __builtin_amdgcn_mfma_f32_16x16x32_f16(a0, bfr[2][kt], acc2, 0, 0, 0);
      if (ard && kt + 2 < 8) a0 = *reinterpret_cast<const half8*>(ap + (kt + 2) * 32 + qo);
      acc0 = __builtin_amdgcn_mfma_f32_16x16x32_f16(a1, bfr[0][kt + 1], acc0, 0, 0, 0);
      acc1 = __builtin_amdgcn_mfma_f32_16x16x32_f16(a1, bfr[1][kt + 1], acc1, 0, 0, 0);
      acc2 = __builtin_amdgcn_mfma_f32_16x16x32_f16(a1, bfr[2][kt + 1], acc2, 0, 0, 0);
    }

    // stage gi(s+1) into the other LDS buffer (nobody reads p^1 this step)
    if (tid < 768 && s < 511) gi_sh[p ^ 1][tid] = gnext;

    // gate math: C row 0 = (q==0, i==0) -> lanes 0..15 hold gh_r/z/n for
    // (batch b, j = wave*16 + lane) in acc0[0]/acc1[0]/acc2[0].
    if (lane < 16) {
      int j = (wave << 4) + lane;
      float ghr = acc0[0] + bhh_sh[j];
      float ghz = acc1[0] + bhh_sh[256 + j];
      float ghn = acc2[0] + bhh_sh[512 + j];
      float gir = gi_sh[p][j], giz = gi_sh[p][256 + j], gin = gi_sh[p][512 + j];
      float r = 1.f / (1.f + __expf(-(gir + ghr)));
      float z = 1.f / (1.f + __expf(-(giz + ghz)));
      float xn = gin + r * ghn;
      float e2 = __expf(2.f * xn);
      float nn = 1.f - 2.f / (e2 + 1.f);           // tanh
      float hnew = (1.f - z) * nn + z * hreg;
      hreg = hnew;
      _Float16 hf = (_Float16)hnew;
      a_sh[p ^ 1][j] = hf;                         // h(s+1) for next step's A
      hid[s * 256 + j] = hf;
    }
    __syncthreads();
    p ^= 1;
  }
}

// ---- kernel 3: out[tok][v] = hidden[tok,:] . w_out[v,:] + b_out[v] ----
template<bool BF>
__global__ __launch_bounds__(256, 2) void k_out(
    const int* __restrict__ flag, const _Float16* __restrict__ hidden,
    const void* __restrict__ w_out, const void* __restrict__ b_out,
    void* __restrict__ out)
{
  if (*flag != (BF ? 1 : 0)) return;
  alignas(16) __shared__ _Float16 Asm[128 * 72];  // [m][k], +8 pad
  alignas(16) __shared__ _Float16 Bsm[128 * 72];  // [n][k], +8 pad
  const int bid = blockIdx.x;
  const int m0 = (bid & 31) * 128;     // 32 m-blocks inner: w_out reuse
  const int n0 = (bid >> 5) * 128;     // 250 n-blocks
  const int tid = threadIdx.x;
  const int wave = tid >> 6, lane = tid & 63;
  const int l15 = lane & 15, q = lane >> 4;
  const int wm = (wave >> 1) * 64, wn = (wave & 1) * 64;

  facc4 acc[4][4] = {};
  float bo[4];
#pragma unroll
  for (int nt = 0; nt < 4; ++nt)
    bo[nt] = ldf<BF>(b_out, n0 + wn + nt * 16 + l15);

  for (int kk = 0; kk < 4; ++kk) {
    int k0 = kk * 64;
#pragma unroll
    for (int r = 0; r < 4; ++r) {
      int row = r * 32 + (tid >> 3);
      int ch = tid & 7;
      *reinterpret_cast<half8*>(&Asm[row * 72 + ch * 8]) =
          *reinterpret_cast<const half8*>(hidden + (m0 + row) * 256 + k0 + ch * 8);
      int wbase = (n0 + row) * 256 + k0 + ch * 8;
      float4v w0 = ld4<BF>(w_out, wbase), w1 = ld4<BF>(w_out, wbase + 4);
      half8 hB;
#pragma unroll
      for (int j = 0; j < 4; ++j) { hB[j] = (_Float16)w0[j]; hB[4 + j] = (_Float16)w1[j]; }
      *reinterpret_cast<half8*>(&Bsm[row * 72 + ch * 8]) = hB;
    }
    __syncthreads();
#pragma unroll
    for (int kt = 0; kt < 2; ++kt) {
      int koff = kt * 32 + q * 8;
      half8 af[4], bf[4];
#pragma unroll
      for (int mt = 0; mt < 4; ++mt)
        af[mt] = *reinterpret_cast<const half8*>(&Asm[(wm + mt * 16 + l15) * 72 + koff]);
#pragma unroll
      for (int nt = 0; nt < 4; ++nt)
        bf[nt] = *reinterpret_cast<const half8*>(&Bsm[(wn + nt * 16 + l15) * 72 + koff]);
#pragma unroll
      for (int mt = 0; mt < 4; ++mt)
#pragma unroll
        for (int nt = 0; nt < 4; ++nt)
          acc[mt][nt] = __builtin_amdgcn_mfma_f32_16x16x32_f16(
              af[mt], bf[nt], acc[mt][nt], 0, 0, 0);
    }
    __syncthreads();
  }
#pragma unroll
  for (int mt = 0; mt < 4; ++mt) {
#pragma unroll
    for (int i = 0; i < 4; ++i) {
      int row = m0 + wm + mt * 16 + q * 4 + i;
#pragma unroll
      for (int nt = 0; nt < 4; ++nt) {
        int col = n0 + wn + nt * 16 + l15;
        float val = acc[mt][nt][i] + bo[nt];
        if constexpr (BF) ((unsigned short*)out)[row * 32000 + col] = f2b(val);
        else              ((float*)out)[row * 32000 + col] = val;
      }
    }
  }
}

extern "C" void kernel_launch(void* const* d_in, const int* in_sizes, int n_in,
                              void* d_out, int out_size, void* d_ws, size_t ws_size,
                              hipStream_t stream) {
  const int* t     = (const int*)d_in[0];
  const void* emb  = d_in[1];
  const void* h0   = d_in[2];
  const void* w_ih = d_in[3];
  const void* w_hh = d_in[4];
  const void* b_ih = d_in[5];
  const void* b_hh = d_in[6];
  const void* w_out = d_in[7];
  const void* b_out = d_in[8];

  float*     gi     = (float*)d_ws;
  _Float16*  hidden = (_Float16*)((char*)d_ws + GI_BYTES);
  int*       flag   = (int*)((char*)d_ws + FLAG_OFF);

  k_detect<<<1, 64, 0, stream>>>((const unsigned int*)emb, flag);

  k_gi<false><<<1024, 256, 0, stream>>>(flag, t, emb, w_ih, b_ih, gi);
  k_gi<true> <<<1024, 256, 0, stream>>>(flag, t, emb, w_ih, b_ih, gi);

  k_scan<false><<<8, 1024, 0, stream>>>(flag, w_hh, b_hh, h0, gi, hidden);
  k_scan<true> <<<8, 1024, 0, stream>>>(flag, w_hh, b_hh, h0, gi, hidden);

  k_out<false><<<8000, 256, 0, stream>>>(flag, hidden, w_out, b_out, d_out);
  k_out<true> <<<8000, 256, 0, stream>>>(flag, hidden, w_out, b_out, d_out);
}